// Round 12
// baseline (207.082 us; speedup 1.0000x reference)
//
#include <hip/hip_runtime.h>
#include <stdint.h>

#define CNT 8192
#define DIM 128

typedef unsigned int u32;

// ---- workspace layout (bytes) ----
#define OFF_POS     ((size_t)0)                            // 3*CNT f32
#define OFF_NEG     (OFF_POS + (size_t)3*CNT*4)            // 3*CNT f32
#define OFF_ROWPART (OFF_NEG + (size_t)3*CNT*4)            // 3*64*CNT u32
#define OFF_COLPART (OFF_ROWPART + (size_t)3*64*CNT*4)     // 3*64*CNT u32
#define OFF_FINROW  (OFF_COLPART + (size_t)3*64*CNT*4)     // 3*CNT u32
#define OFF_FINCOL  (OFF_FINROW + (size_t)3*CNT*4)         // 3*CNT u32
#define OFF_RNORM   (OFF_FINCOL + (size_t)3*CNT*4)         // 6*CNT f32
#define OFF_U       (OFF_RNORM + (size_t)6*CNT*4)          // 6*CNT f32
#define OFF_V       (OFF_U + (size_t)6*CNT*4)              // 6*CNT f32
#define OFF_MPART   (OFF_V + (size_t)6*CNT*4)              // 6144*5 f32
#define OFF_PSUM    (OFF_MPART + (size_t)6144*5*4)         // 192*200 f32
#define OFF_XNB     (OFF_PSUM + (size_t)192*200*4)         // 6*CNT*DIM bf16
// total ~27 MiB

typedef __attribute__((ext_vector_type(8))) short short8;
typedef __attribute__((ext_vector_type(4))) float f32x4;

__device__ __forceinline__ float fract1(float x){
#if __has_builtin(__builtin_amdgcn_fractf)
  return __builtin_amdgcn_fractf(x);
#else
  return x - floorf(x);
#endif
}
__device__ __forceinline__ u32 umax2(u32 a, u32 b){ return a > b ? a : b; }
__device__ __forceinline__ u32 umax3(u32 a, u32 b, u32 c){ u32 t = a > b ? a : b; return t > c ? t : c; }
__device__ __forceinline__ u32 umin2(u32 a, u32 b){ return a < b ? a : b; }

__device__ __forceinline__ float block_sum(float x, float* red, int tid){
  #pragma unroll
  for (int m=1;m<64;m<<=1) x += __shfl_xor(x, m, 64);
  if ((tid & 63) == 0) red[tid>>6] = x;
  __syncthreads();
  const float r = red[0]+red[1]+red[2]+red[3];
  __syncthreads();
  return r;
}

// row-normalize -> bf16 (A-side segments 0,2,4 pre-scaled by 0.25) + reciprocal norms
__global__ __launch_bounds__(256) void knorm(const float* __restrict__ in,
                                             unsigned int* __restrict__ xnb32,
                                             float* __restrict__ rnorm){
  const int row  = blockIdx.x*4 + (threadIdx.x>>6);
  const int lane = threadIdx.x & 63;
  const float2 v = *(const float2*)(in + (size_t)row*DIM + lane*2);
  float ss = v.x*v.x + v.y*v.y;
  #pragma unroll
  for (int m=1;m<64;m<<=1) ss += __shfl_xor(ss, m, 64);
  const float rn = 1.0f / sqrtf(ss);
  const float sc = ((row & CNT) ? 1.0f : 0.25f) * rn;
  unsigned int ux = __float_as_uint(v.x*sc), uy = __float_as_uint(v.y*sc);
  ux = (ux + 0x7FFFu + ((ux>>16)&1u)) >> 16;
  uy = (uy + 0x7FFFu + ((uy>>16)&1u)) >> 16;
  xnb32[(size_t)row*64 + lane] = ux | (uy<<16);
  if (lane == 0) rnorm[row] = rn;
}

// ---------------- MFMA bf16 GEMM, 128x128 tile, A in registers (hoisted), Y-only LDS dbuf ----------------
// acc = dot/4 (A pre-scaled). key = fract(acc): larger key == smaller dm (dm = 1/dot + eps).
// Row pack: [key25 | ~col7]; Col pack: [key26 | ~row6]. u32 max = argmax + lowest-idx ties.
// Global partials: u32 [inv_key19 | index13], min-reduced in kred.
__global__ __launch_bounds__(256, 3) void kgemm(const unsigned short* __restrict__ xnb,
    u32* __restrict__ rowpart, u32* __restrict__ colpart){
  __shared__ __align__(16) char LB[19456];   // Y dbuf 2x8KB @0; epilogue: rowbuf 18KB @0, colred 1KB @18432
  const int lin = blockIdx.x + (blockIdx.y<<6) + (blockIdx.z<<12);
  const int wg  = (lin & 7)*1536 + (lin >> 3);           // bijective XCD chunking
  const int bx = wg & 63, by = (wg >> 6) & 63, pair = wg >> 12;
  const int xo3[3] = {0, 2*CNT, 4*CNT};
  const int yo3[3] = {CNT, 5*CNT, 3*CNT};
  const unsigned short* __restrict__ X = xnb + (size_t)xo3[pair]*DIM;
  const unsigned short* __restrict__ Y = xnb + (size_t)yo3[pair]*DIM;
  const int brow = by*128, bcol = bx*128;
  const int tid = threadIdx.x, lane = tid & 63, wid = tid >> 6;
  const int wr = wid >> 1, wc = wid & 1;                 // 2x2 waves, 64x64 tiles
  const int lrow = lane & 15, kgrp = lane >> 4;

  // Y staging sources (16B/lane/inst)
  const int rr16 = lane >> 2;
  const int slog = (lane&3) ^ ((lane>>3)&3);             // logical k-slot this phys slot holds
  const unsigned short* gB0 = Y + (size_t)(bcol + (wid*2+0)*16 + rr16)*DIM + slog*8;
  const unsigned short* gB1 = Y + (size_t)(bcol + (wid*2+1)*16 + rr16)*DIM + slog*8;

#define STAGEY(c) do{ \
    char* LY_ = LB + ((c)&1)*8192; \
    __builtin_amdgcn_global_load_lds((const __attribute__((address_space(1))) void*)(gB0 + (c)*32), \
        (__attribute__((address_space(3))) void*)(LY_ + (wid*2+0)*1024), 16, 0, 0); \
    __builtin_amdgcn_global_load_lds((const __attribute__((address_space(1))) void*)(gB1 + (c)*32), \
        (__attribute__((address_space(3))) void*)(LY_ + (wid*2+1)*1024), 16, 0, 0); \
  }while(0)

  // A fragments: all 16 hoisted to prologue (latency resolves once, under stage+barrier).
  // Fragment layout == contiguous 16B at (row = brow+wr*64+m*16+lrow, k = c*32 + kgrp*8).
  const unsigned short* gA = X + (size_t)(brow + wr*64 + lrow)*DIM + kgrp*8;
  STAGEY(0);
  short8 Afr[4][4];
  #pragma unroll
  for (int c=0;c<4;c++)
    #pragma unroll
    for (int m=0;m<4;m++)
      Afr[c][m] = *(const short8*)(gA + (size_t)m*16*DIM + c*32);

  f32x4 acc[4][4];
  #pragma unroll
  for (int m=0;m<4;m++)
    #pragma unroll
    for (int n=0;n<4;n++)
      acc[m][n] = (f32x4){0.f,0.f,0.f,0.f};

  __syncthreads();

  const int kb = (kgrp*16) ^ (((lrow>>1)&3) << 4);
  #pragma unroll
  for (int c=0;c<4;c++){
    if (c<3) STAGEY(c+1);
    const char* bB = LB + (c&1)*8192 + (wc*64 + lrow)*64 + kb;
    short8 bv[4];
    #pragma unroll
    for (int n=0;n<4;n++) bv[n] = *(const short8*)(bB + n*1024);
    #pragma unroll
    for (int m=0;m<4;m++)
      #pragma unroll
      for (int n=0;n<4;n++)
        acc[m][n] = __builtin_amdgcn_mfma_f32_16x16x32_bf16(Afr[c][m], bv[n], acc[m][n], 0, 0, 0);
    if (c<3) __syncthreads();
  }

  // diagonal: acc=0 -> key 0 = minimal (reference adds BIG)
  if (bx == by && wr == wc && kgrp == (lrow >> 2)){
    #pragma unroll
    for (int r=0;r<4;r++)
      if ((lrow & 3) == r){
        #pragma unroll
        for (int m=0;m<4;m++) acc[m][m][r] = 0.0f;
      }
  }

  // packing + max-trees
  const int colb_loc = wc*64 + lrow;
  u32 orvr[4];
  #pragma unroll
  for (int n=0;n<4;n++) orvr[n] = (u32)(127 - colb_loc - n*16);

  u32 pkc[4] = {0u,0u,0u,0u};
  u32 rpk[16];
  #pragma unroll
  for (int m=0;m<4;m++){
    #pragma unroll
    for (int r=0;r<4;r++){
      const u32 orvc = (u32)(63 - (m*16 + kgrp*4 + r));
      u32 kb2[4];
      #pragma unroll
      for (int n=0;n<4;n++)
        kb2[n] = __float_as_uint(fract1(acc[m][n][r]));
      const u32 b0 = (kb2[0] & 0xFFFFFF80u) | orvr[0];
      const u32 b1 = (kb2[1] & 0xFFFFFF80u) | orvr[1];
      const u32 b2 = (kb2[2] & 0xFFFFFF80u) | orvr[2];
      const u32 b3 = (kb2[3] & 0xFFFFFF80u) | orvr[3];
      rpk[m*4+r] = umax2(umax3(b0, b1, b2), b3);
      pkc[0] = umax2(pkc[0], (kb2[0] & 0xFFFFFFC0u) | orvc);
      pkc[1] = umax2(pkc[1], (kb2[1] & 0xFFFFFFC0u) | orvc);
      pkc[2] = umax2(pkc[2], (kb2[2] & 0xFFFFFFC0u) | orvc);
      pkc[3] = umax2(pkc[3], (kb2[3] & 0xFFFFFFC0u) | orvc);
    }
  }

  // col: combine across kgrp lanes (row id embedded -> shuffle-max keeps winner)
  #pragma unroll
  for (int n=0;n<4;n++){
    u32 o = (u32)__shfl_xor((int)pkc[n], 16, 64); pkc[n] = umax2(pkc[n], o);
    o = (u32)__shfl_xor((int)pkc[n], 32, 64);     pkc[n] = umax2(pkc[n], o);
  }

  __syncthreads();                                  // Y dbuf consumed; reuse LDS
  u32* rowbuf = (u32*)LB;                           // [128][36] u32 = 18KB
  u32* colred = (u32*)(LB + 18432);                 // [2][128] u32 = 1KB
  {
    const int slot = wc*16 + lrow;
    #pragma unroll
    for (int m=0;m<4;m++)
      #pragma unroll
      for (int r=0;r<4;r++){
        const int row = wr*64 + m*16 + kgrp*4 + r;
        rowbuf[row*36 + slot] = rpk[m*4+r];
      }
    if (kgrp == 0){
      #pragma unroll
      for (int n=0;n<4;n++)
        colred[wr*128 + wc*64 + n*16 + lrow] = pkc[n];
    }
  }
  __syncthreads();

  if (tid < 128){
    const u32* base = rowbuf + tid*36;
    u32 best = 0u;
    #pragma unroll
    for (int q=0;q<8;q++){
      const uint4 t = *(const uint4*)(base + q*4);
      best = umax2(best, umax2(umax3(t.x, t.y, t.z), t.w));
    }
    const int colg = 127 - (int)(best & 127u);
    rowpart[((size_t)pair*64 + bx)*CNT + (brow + tid)] =
        ((~best) & 0xFFFFE000u) | (u32)(bcol + colg);
  } else {
    const int c = tid - 128;
    const u32 a0 = colred[c], a1 = colred[128 + c];
    const u32 w = umax2(a0, a1);
    const int rloc = (a1 > a0 ? 64 : 0) + (63 - (int)(w & 63u));
    colpart[((size_t)pair*64 + by)*CNT + (bcol + c)] =
        ((~w) & 0xFFFFE000u) | (u32)(brow + rloc);
  }
#undef STAGEY
}

// coalesced reduction of row/col partials (64 blocks each) -> finrow/fincol
__global__ __launch_bounds__(256) void kred(const u32* __restrict__ rowpart, const u32* __restrict__ colpart,
    u32* __restrict__ finrow, u32* __restrict__ fincol){
  __shared__ u32 lds[4][128];
  const int tid = threadIdx.x, w = tid>>6, lane = tid&63;
  const int b = blockIdx.x;                        // 192 blocks
  const int p = b >> 6, ibase = (b & 63) << 7;     // 128 i's per block
  uint2 mn = {0xFFFFFFFFu, 0xFFFFFFFFu};
  #pragma unroll 4
  for (int t=0;t<16;t++){
    const int bx = w*16 + t;
    const uint2 vv = *(const uint2*)(rowpart + ((size_t)p*64 + bx)*CNT + ibase + lane*2);
    mn.x = umin2(mn.x, vv.x); mn.y = umin2(mn.y, vv.y);
  }
  lds[w][lane*2] = mn.x; lds[w][lane*2+1] = mn.y;
  __syncthreads();
  if (tid < 128)
    finrow[(size_t)p*CNT + ibase + tid] = umin2(umin2(lds[0][tid], lds[1][tid]), umin2(lds[2][tid], lds[3][tid]));
  __syncthreads();
  mn.x = 0xFFFFFFFFu; mn.y = 0xFFFFFFFFu;
  #pragma unroll 4
  for (int t=0;t<16;t++){
    const int by = w*16 + t;
    const uint2 vv = *(const uint2*)(colpart + ((size_t)p*64 + by)*CNT + ibase + lane*2);
    mn.x = umin2(mn.x, vv.x); mn.y = umin2(mn.y, vv.y);
  }
  lds[w][lane*2] = mn.x; lds[w][lane*2+1] = mn.y;
  __syncthreads();
  if (tid < 128)
    fincol[(size_t)p*CNT + ibase + tid] = umin2(umin2(lds[0][tid], lds[1][tid]), umin2(lds[2][tid], lds[3][tid]));
}

// pick hard negative + dots via rnorm + u,v + per-block moment partials
__global__ __launch_bounds__(256) void kpick(const float* __restrict__ descs,
    const float* __restrict__ rnorm,
    const u32* __restrict__ finrow, const u32* __restrict__ fincol,
    float* __restrict__ pos, float* __restrict__ neg,
    float* __restrict__ u, float* __restrict__ v, float* __restrict__ mpart){
  __shared__ float sred[4][5];
  const int tid = threadIdx.x;
  const int w4 = tid >> 6, lane = tid & 63;
  const int e = blockIdx.x*4 + w4;                 // 0..24575
  const int p = e >> 13, i = e & (CNT-1);
  const int xo[3] = {0, 2*CNT, 4*CNT};
  const int yo[3] = {CNT, 5*CNT, 3*CNT};
  const u32 rv = finrow[(size_t)p*CNT + i];
  const u32 cv = fincol[(size_t)p*CNT + i];
  int orow;
  if ((rv & 0xFFFFE000u) < (cv & 0xFFFFE000u)) orow = yo[p] + (int)(rv & 0x1FFFu);
  else                                          orow = xo[p] + (int)(cv & 0x1FFFu);
  const float2 va = *(const float2*)(descs + (size_t)(xo[p]+i)*DIM + lane*2);
  const float2 vp = *(const float2*)(descs + (size_t)(yo[p]+i)*DIM + lane*2);
  const float2 vn = *(const float2*)(descs + (size_t)orow*DIM + lane*2);
  float sap = va.x*vp.x + va.y*vp.y;
  float san = va.x*vn.x + va.y*vn.y;
  #pragma unroll
  for (int m=1;m<64;m<<=1){
    sap += __shfl_xor(sap, m, 64);
    san += __shfl_xor(san, m, 64);
  }
  if (lane == 0){
    const float rna = rnorm[xo[p]+i];
    const float dp = sap * rna * rnorm[yo[p]+i];
    const float dn = san * rna * rnorm[orow];
    pos[p*CNT + i] = dp; neg[p*CNT + i] = dn;
    const float omp_ = 1.f - dp, sqp = sqrtf(2.f*omp_ + 1e-12f), up = omp_ - sqp;
    const float omn_ = 1.f - dn, sqn = sqrtf(2.f*omn_ + 1e-12f), un = omn_ - sqn;
    u[p*CNT + i] = up;           v[p*CNT + i] = sqp;
    u[3*CNT + p*CNT + i] = un;   v[3*CNT + p*CNT + i] = sqn;
    const float cup = up + 0.35f, cvp = sqp - 0.80f;
    const float cun = un + 0.35f, cvn = sqn - 0.80f;
    sred[w4][0] = up + un;
    sred[w4][1] = sqp + sqn;
    sred[w4][2] = cup*cup + cun*cun;
    sred[w4][3] = cup*cvp + cun*cvn;
    sred[w4][4] = cvp*cvp + cvn*cvn;
  }
  __syncthreads();
  if (tid < 5)
    mpart[blockIdx.x*5 + tid] = sred[0][tid] + sred[1][tid] + sred[2][tid] + sred[3][tid];
}

// kbce (kmom folded in): each block re-reduces mpart (L2-resident) then does its 256-elem chunk
__global__ __launch_bounds__(256) void kbce(const float* __restrict__ u, const float* __restrict__ v,
    const float* __restrict__ mpart, float* __restrict__ psum){
  __shared__ float red[4];
  __shared__ float lu[256], lv[256];
  const int tid = threadIdx.x, b = blockIdx.x;
  lu[tid] = u[b*256 + tid];
  lv[tid] = v[b*256 + tid];
  float a0=0.f,a1=0.f,a2=0.f,a3=0.f,a4=0.f;
  for (int i = tid; i < 6144; i += 256){
    const float* mp = mpart + (size_t)i*5;
    a0+=mp[0]; a1+=mp[1]; a2+=mp[2]; a3+=mp[3]; a4+=mp[4];
  }
  a0 = block_sum(a0, red, tid);
  a1 = block_sum(a1, red, tid);
  a2 = block_sum(a2, red, tid);
  a3 = block_sum(a3, red, tid);
  a4 = block_sum(a4, red, tid);      // barriers also publish lu/lv
  if (tid < 200){
    const float N = 49152.0f;
    const float mu_u = a0/N, mu_v = a1/N;
    const float du = mu_u + 0.35f, dv = mu_v - 0.80f;
    const float Suu = a2 - N*du*du;
    const float Suv = a3 - N*du*dv;
    const float Svv = a4 - N*dv*dv;
    const float a = -1.0f + 0.01f*(float)tid;
    const float mean = a*mu_u + mu_v;
    const float istd = 1.0f / sqrtf((a*a*Suu + 2.0f*a*Suv + Svv) / 49151.0f);
    const float sgn = (b < 96) ? 1.0f : -1.0f;     // first 3*CNT are label=1
    const float zi = istd*sgn;
    const float zm = mean*zi;
    float s = 0.0f;
    #pragma unroll 8
    for (int j=0;j<256;j++){
      const float z = fmaf(fmaf(a, lu[j], lv[j]), zi, -zm);
      s += fmaxf(z, 0.0f) + __logf(1.0f + __expf(-fabsf(z)));
    }
    psum[b*200 + tid] = s;
  }
}

// argmin(bce) -> alpha; losses, mask ratio, l_mean; 8 outputs
__global__ __launch_bounds__(256) void kfinal(const float* __restrict__ pos, const float* __restrict__ neg,
    const float* __restrict__ psum, const float* __restrict__ l_a_adv, const float* __restrict__ l_p_adv,
    float* __restrict__ out){
  __shared__ float sbce[200];
  __shared__ float sal[2];
  __shared__ float red[4];
  const int tid = threadIdx.x;
  if (tid < 200){
    float s = 0.f;
    for (int b=0;b<192;b++) s += psum[b*200 + tid];
    sbce[tid] = s;
  }
  __syncthreads();
  if (tid == 0){
    float best = sbce[0]; int bk = 0;
    for (int k=1;k<200;k++){
      const float vv = sbce[k];
      if (vv < best){ best = vv; bk = k; }
    }
    const float aopt = -1.0f + 0.01f*(float)bk;
    sal[0] = aopt;
    sal[1] = aopt * 0.005f;
  }
  __syncthreads();
  const float alpha = sal[1];

  float sc=0.f, sar=0.f, saa=0.f, sm=0.f, sla=0.f, slp=0.f;
  for (int i = tid; i < CNT; i += 256){
    const float pap = pos[i],        nap = neg[i];
    const float par = pos[CNT+i],    nar = neg[CNT+i];
    const float paa = pos[2*CNT+i],  naa = neg[2*CNT+i];
    const float cp = fminf(fmaxf(pap, -1.0f), 1.0f);
    const float cn = fminf(fmaxf(nap, -1.0f), 1.0f);
    const float m = (0.36f + acosf(cp) - acosf(cn) > 0.0f) ? 1.0f : 0.0f;
    #define DDIST(d) (alpha*(1.0f-(d)) + (1.0f-alpha)*sqrtf(2.0f*(1.0f-(d)) + 1e-12f))
    sc  += (DDIST(pap) - DDIST(nap)) * m;
    sar += (l_p_adv[i]*DDIST(par) - DDIST(nar)) * m;
    saa += (l_a_adv[i]*DDIST(paa) - DDIST(naa)) * m;
    sm  += m;
    sla += l_a_adv[i];
    slp += l_p_adv[i];
  }
  float vals[6] = {sc, sar, saa, sm, sla, slp};
  float tot[6];
  for (int vv=0; vv<6; vv++){
    tot[vv] = block_sum(vals[vv], red, tid);
  }
  if (tid == 0){
    const float lc  = tot[0] / (float)CNT;
    const float lar = tot[1] / (float)CNT;
    const float laa = tot[2] / (float)CNT;
    out[0] = (lc + lar + laa) / 3.0f;
    out[1] = lc;
    out[2] = lar;
    out[3] = laa;
    out[4] = (tot[4]/(float)CNT + tot[5]/(float)CNT) * 0.5f;
    out[5] = sal[1];
    out[6] = sal[0];
    out[7] = tot[3] / (float)CNT;
  }
}

extern "C" void kernel_launch(void* const* d_in, const int* in_sizes, int n_in,
                              void* d_out, int out_size, void* d_ws, size_t ws_size,
                              hipStream_t stream) {
  const float* descs = (const float*)d_in[0];
  const float* l_a   = (const float*)d_in[1];
  const float* l_p   = (const float*)d_in[2];
  float* out = (float*)d_out;
  char* ws = (char*)d_ws;

  float* pos = (float*)(ws + OFF_POS);
  float* neg = (float*)(ws + OFF_NEG);
  u32* rowpart = (u32*)(ws + OFF_ROWPART);
  u32* colpart = (u32*)(ws + OFF_COLPART);
  u32* finrow  = (u32*)(ws + OFF_FINROW);
  u32* fincol  = (u32*)(ws + OFF_FINCOL);
  float* rnorm = (float*)(ws + OFF_RNORM);
  float* u     = (float*)(ws + OFF_U);
  float* v     = (float*)(ws + OFF_V);
  float* mpart = (float*)(ws + OFF_MPART);
  float* psum  = (float*)(ws + OFF_PSUM);
  unsigned int* xnb32 = (unsigned int*)(ws + OFF_XNB);
  const unsigned short* xnb = (const unsigned short*)(ws + OFF_XNB);

  knorm  <<<(6*CNT)/4, 256, 0, stream>>>(descs, xnb32, rnorm);
  kgemm  <<<dim3(64,64,3), 256, 0, stream>>>(xnb, rowpart, colpart);
  kred   <<<192, 256, 0, stream>>>(rowpart, colpart, finrow, fincol);
  kpick  <<<(3*CNT)/4, 256, 0, stream>>>(descs, rnorm, finrow, fincol, pos, neg, u, v, mpart);
  kbce   <<<192, 256, 0, stream>>>(u, v, mpart, psum);
  kfinal <<<1, 256, 0, stream>>>(pos, neg, psum, l_a, l_p, out);
}

// Round 13
// 172.654 us; speedup vs baseline: 1.1994x; 1.1994x over previous
//
#include <hip/hip_runtime.h>
#include <stdint.h>

#define CNT 8192
#define DIM 128

typedef unsigned int u32;

// ---- workspace layout (bytes) ----
#define OFF_POS     ((size_t)0)                            // 3*CNT f32
#define OFF_NEG     (OFF_POS + (size_t)3*CNT*4)            // 3*CNT f32
#define OFF_ROWPART (OFF_NEG + (size_t)3*CNT*4)            // 3*64*CNT u32
#define OFF_COLPART (OFF_ROWPART + (size_t)3*64*CNT*4)     // 3*64*CNT u32
#define OFF_RNORM   (OFF_COLPART + (size_t)3*64*CNT*4)     // 6*CNT f32
#define OFF_U       (OFF_RNORM + (size_t)6*CNT*4)          // 6*CNT f32
#define OFF_V       (OFF_U + (size_t)6*CNT*4)              // 6*CNT f32
#define OFF_MPART   (OFF_V + (size_t)6*CNT*4)              // 192*5 f32
#define OFF_PSUM    (OFF_MPART + (size_t)4096)             // 192*200 f32
#define OFF_XNB     (OFF_PSUM + (size_t)192*200*4)         // 6*CNT*DIM bf16
// total ~26 MiB

typedef __attribute__((ext_vector_type(8))) short short8;
typedef __attribute__((ext_vector_type(4))) float f32x4;

__device__ __forceinline__ float fract1(float x){
#if __has_builtin(__builtin_amdgcn_fractf)
  return __builtin_amdgcn_fractf(x);
#else
  return x - floorf(x);
#endif
}
__device__ __forceinline__ u32 umax2(u32 a, u32 b){ return a > b ? a : b; }
__device__ __forceinline__ u32 umax3(u32 a, u32 b, u32 c){ u32 t = a > b ? a : b; return t > c ? t : c; }
__device__ __forceinline__ u32 umin2(u32 a, u32 b){ return a < b ? a : b; }

__device__ __forceinline__ float block_sum(float x, float* red, int tid){
  #pragma unroll
  for (int m=1;m<64;m<<=1) x += __shfl_xor(x, m, 64);
  if ((tid & 63) == 0) red[tid>>6] = x;
  __syncthreads();
  const float r = red[0]+red[1]+red[2]+red[3];
  __syncthreads();
  return r;
}

// row-normalize -> bf16 (A-side segments 0,2,4 pre-scaled by 0.25) + reciprocal norms
__global__ __launch_bounds__(256) void knorm(const float* __restrict__ in,
                                             unsigned int* __restrict__ xnb32,
                                             float* __restrict__ rnorm){
  const int row  = blockIdx.x*4 + (threadIdx.x>>6);
  const int lane = threadIdx.x & 63;
  const float2 v = *(const float2*)(in + (size_t)row*DIM + lane*2);
  float ss = v.x*v.x + v.y*v.y;
  #pragma unroll
  for (int m=1;m<64;m<<=1) ss += __shfl_xor(ss, m, 64);
  const float rn = 1.0f / sqrtf(ss);
  const float sc = ((row & CNT) ? 1.0f : 0.25f) * rn;
  unsigned int ux = __float_as_uint(v.x*sc), uy = __float_as_uint(v.y*sc);
  ux = (ux + 0x7FFFu + ((ux>>16)&1u)) >> 16;
  uy = (uy + 0x7FFFu + ((uy>>16)&1u)) >> 16;
  xnb32[(size_t)row*64 + lane] = ux | (uy<<16);
  if (lane == 0) rnorm[row] = rn;
}

// ---------------- MFMA bf16 GEMM, BK=32 dbuf (round-7 structure, proven 83 us) ----------------
// acc = dot/4 (A pre-scaled). key = fract(acc): larger key == smaller dm (dm = 1/dot + eps).
// In-block packs: row [key25 | ~col7], col [key26 | ~row6] -> u32 max = argmax + lowest-idx ties.
// Global partials: u32 [inv_key19 | index13], min-reduced in kpickred.
__global__ __launch_bounds__(256) void kgemm(const unsigned short* __restrict__ xnb,
    u32* __restrict__ rowpart, u32* __restrict__ colpart){
  __shared__ __align__(16) unsigned short S[4][128*32];   // 32 KB: buf0{X,Y}, buf1{X,Y}
  const int pair = blockIdx.z;
  const int xo3[3] = {0, 2*CNT, 4*CNT};
  const int yo3[3] = {CNT, 5*CNT, 3*CNT};
  const unsigned short* __restrict__ X = xnb + (size_t)xo3[pair]*DIM;
  const unsigned short* __restrict__ Y = xnb + (size_t)yo3[pair]*DIM;
  const int brow = blockIdx.y*128, bcol = blockIdx.x*128;
  const int tid = threadIdx.x, lane = tid & 63, wid = tid >> 6;
  const int wr = wid >> 1, wc = wid & 1;           // 2x2 waves, 64x64 tiles
  const int lrow = lane & 15, kgrp = lane >> 4;

  // per-lane staging sources (16B/lane/inst), hoisted once; chunk advance folded into pointer
  const int j0 = wid*2, j1 = wid*2 + 1;
  const int r0 = j0*16 + (lane>>2), r1 = j1*16 + (lane>>2);
  const int slog = (lane&3) ^ ((lane>>3)&3);       // logical k-slot this phys slot holds
  const unsigned short* gx0 = X + (size_t)(brow + r0)*DIM + slog*8;
  const unsigned short* gx1 = X + (size_t)(brow + r1)*DIM + slog*8;
  const unsigned short* gy0 = Y + (size_t)(bcol + r0)*DIM + slog*8;
  const unsigned short* gy1 = Y + (size_t)(bcol + r1)*DIM + slog*8;

#define STAGEC(c) do{ \
    unsigned short* LX = S[((c)&1)*2]; \
    unsigned short* LY = S[((c)&1)*2 + 1]; \
    __builtin_amdgcn_global_load_lds((const __attribute__((address_space(1))) void*)(gx0 + (c)*32), \
        (__attribute__((address_space(3))) void*)(LX + j0*512), 16, 0, 0); \
    __builtin_amdgcn_global_load_lds((const __attribute__((address_space(1))) void*)(gx1 + (c)*32), \
        (__attribute__((address_space(3))) void*)(LX + j1*512), 16, 0, 0); \
    __builtin_amdgcn_global_load_lds((const __attribute__((address_space(1))) void*)(gy0 + (c)*32), \
        (__attribute__((address_space(3))) void*)(LY + j0*512), 16, 0, 0); \
    __builtin_amdgcn_global_load_lds((const __attribute__((address_space(1))) void*)(gy1 + (c)*32), \
        (__attribute__((address_space(3))) void*)(LY + j1*512), 16, 0, 0); \
  }while(0)

  f32x4 acc[4][4];
  #pragma unroll
  for (int m=0;m<4;m++)
    #pragma unroll
    for (int n=0;n<4;n++)
      acc[m][n] = (f32x4){0.f,0.f,0.f,0.f};

  STAGEC(0);
  __syncthreads();

  const int swzb = ((lrow>>1)&3) << 4;
  #pragma unroll
  for (int c=0;c<4;c++){
    if (c<3) STAGEC(c+1);
    const char* LX = (const char*)S[(c&1)*2];
    const char* LY = (const char*)S[(c&1)*2 + 1];
    const int kb = (kgrp*16) ^ swzb;
    short8 av[4], bv[4];
    #pragma unroll
    for (int m=0;m<4;m++){
      av[m] = *(const short8*)(LX + (wr*64 + m*16 + lrow)*64 + kb);
      bv[m] = *(const short8*)(LY + (wc*64 + m*16 + lrow)*64 + kb);
    }
    #pragma unroll
    for (int m=0;m<4;m++)
      #pragma unroll
      for (int n=0;n<4;n++)
        acc[m][n] = __builtin_amdgcn_mfma_f32_16x16x32_bf16(av[m], bv[n], acc[m][n], 0, 0, 0);
    if (c<3) __syncthreads();
  }

  // diagonal: acc=0 -> key 0 = minimal (reference adds BIG)
  if (blockIdx.x == blockIdx.y && wr == wc && kgrp == (lrow >> 2)){
    #pragma unroll
    for (int r=0;r<4;r++)
      if ((lrow & 3) == r){
        #pragma unroll
        for (int m=0;m<4;m++) acc[m][m][r] = 0.0f;
      }
  }

  // packing + max-trees (v_fract / v_and_or / v_max3 shaped)
  const int colb_loc = wc*64 + lrow;
  u32 orvr[4];
  #pragma unroll
  for (int n=0;n<4;n++) orvr[n] = (u32)(127 - colb_loc - n*16);

  u32 pkc[4] = {0u,0u,0u,0u};
  u32 rpk[16];
  #pragma unroll
  for (int m=0;m<4;m++){
    #pragma unroll
    for (int r=0;r<4;r++){
      const u32 orvc = (u32)(63 - (m*16 + kgrp*4 + r));
      u32 kb2[4];
      #pragma unroll
      for (int n=0;n<4;n++)
        kb2[n] = __float_as_uint(fract1(acc[m][n][r]));
      const u32 b0 = (kb2[0] & 0xFFFFFF80u) | orvr[0];
      const u32 b1 = (kb2[1] & 0xFFFFFF80u) | orvr[1];
      const u32 b2 = (kb2[2] & 0xFFFFFF80u) | orvr[2];
      const u32 b3 = (kb2[3] & 0xFFFFFF80u) | orvr[3];
      rpk[m*4+r] = umax2(umax3(b0, b1, b2), b3);
      pkc[0] = umax2(pkc[0], (kb2[0] & 0xFFFFFFC0u) | orvc);
      pkc[1] = umax2(pkc[1], (kb2[1] & 0xFFFFFFC0u) | orvc);
      pkc[2] = umax2(pkc[2], (kb2[2] & 0xFFFFFFC0u) | orvc);
      pkc[3] = umax2(pkc[3], (kb2[3] & 0xFFFFFFC0u) | orvc);
    }
  }

  // col: combine across kgrp lanes (row id embedded -> shuffle-max keeps winner)
  #pragma unroll
  for (int n=0;n<4;n++){
    u32 o = (u32)__shfl_xor((int)pkc[n], 16, 64); pkc[n] = umax2(pkc[n], o);
    o = (u32)__shfl_xor((int)pkc[n], 32, 64);     pkc[n] = umax2(pkc[n], o);
  }

  __syncthreads();                                  // tiles consumed; reuse LDS
  u32* rowbuf = (u32*)S;                            // [128][36] u32 = 18KB
  u32* colred = (u32*)((char*)S + 20480);           // [2][128] u32 = 1KB
  {
    const int slot = wc*16 + lrow;
    #pragma unroll
    for (int m=0;m<4;m++)
      #pragma unroll
      for (int r=0;r<4;r++){
        const int row = wr*64 + m*16 + kgrp*4 + r;
        rowbuf[row*36 + slot] = rpk[m*4+r];
      }
    if (kgrp == 0){
      #pragma unroll
      for (int n=0;n<4;n++)
        colred[wr*128 + wc*64 + n*16 + lrow] = pkc[n];
    }
  }
  __syncthreads();

  if (tid < 128){
    const u32* base = rowbuf + tid*36;
    u32 best = 0u;
    #pragma unroll
    for (int q=0;q<8;q++){
      const uint4 t = *(const uint4*)(base + q*4);
      best = umax2(best, umax2(umax3(t.x, t.y, t.z), t.w));
    }
    const int colg = 127 - (int)(best & 127u);
    rowpart[((size_t)pair*64 + blockIdx.x)*CNT + (brow + tid)] =
        ((~best) & 0xFFFFE000u) | (u32)(bcol + colg);
  } else {
    const int c = tid - 128;
    const u32 a0 = colred[c], a1 = colred[128 + c];
    const u32 w = umax2(a0, a1);
    const int rloc = (a1 > a0 ? 64 : 0) + (63 - (int)(w & 63u));
    colpart[((size_t)pair*64 + blockIdx.y)*CNT + (bcol + c)] =
        ((~w) & 0xFFFFE000u) | (u32)(brow + rloc);
  }
#undef STAGEC
}

// fused: coalesced 64-way min of row/col partials (in LDS) + hard-negative pick + dots + u,v + moments
// 192 blocks; block b: pair p = b/64, entities ibase..ibase+127.
__global__ __launch_bounds__(256) void kpickred(const float* __restrict__ descs,
    const float* __restrict__ rnorm,
    const u32* __restrict__ rowpart, const u32* __restrict__ colpart,
    float* __restrict__ pos, float* __restrict__ neg,
    float* __restrict__ u, float* __restrict__ v, float* __restrict__ mpart){
  __shared__ u32 scr[4][128];
  __shared__ u32 rvs[128], cvs[128];
  __shared__ float sred[4][5];
  const int tid = threadIdx.x, w = tid>>6, lane = tid&63;
  const int b = blockIdx.x;
  const int p = b >> 6, ibase = (b & 63) << 7;
  const int xo[3] = {0, 2*CNT, 4*CNT};
  const int yo[3] = {CNT, 5*CNT, 3*CNT};

  uint2 mn = {0xFFFFFFFFu, 0xFFFFFFFFu};
  #pragma unroll 4
  for (int t=0;t<16;t++){
    const int bxi = w*16 + t;
    const uint2 vv = *(const uint2*)(rowpart + ((size_t)p*64 + bxi)*CNT + ibase + lane*2);
    mn.x = umin2(mn.x, vv.x); mn.y = umin2(mn.y, vv.y);
  }
  scr[w][lane*2] = mn.x; scr[w][lane*2+1] = mn.y;
  __syncthreads();
  if (tid < 128)
    rvs[tid] = umin2(umin2(scr[0][tid], scr[1][tid]), umin2(scr[2][tid], scr[3][tid]));
  __syncthreads();
  mn.x = 0xFFFFFFFFu; mn.y = 0xFFFFFFFFu;
  #pragma unroll 4
  for (int t=0;t<16;t++){
    const int byi = w*16 + t;
    const uint2 vv = *(const uint2*)(colpart + ((size_t)p*64 + byi)*CNT + ibase + lane*2);
    mn.x = umin2(mn.x, vv.x); mn.y = umin2(mn.y, vv.y);
  }
  scr[w][lane*2] = mn.x; scr[w][lane*2+1] = mn.y;
  __syncthreads();
  if (tid < 128)
    cvs[tid] = umin2(umin2(scr[0][tid], scr[1][tid]), umin2(scr[2][tid], scr[3][tid]));
  __syncthreads();

  // phase 2: 4 waves x 32 entities; per entity one wave computes both dots
  float s0=0.f, s1=0.f, s2=0.f, s3=0.f, s4=0.f;
  #pragma unroll 2
  for (int j=0;j<32;j++){
    const int il = w*32 + j;
    const int i = ibase + il;
    const u32 rv = rvs[il], cv = cvs[il];
    int orow;
    if ((rv & 0xFFFFE000u) < (cv & 0xFFFFE000u)) orow = yo[p] + (int)(rv & 0x1FFFu);
    else                                          orow = xo[p] + (int)(cv & 0x1FFFu);
    const float2 va = *(const float2*)(descs + (size_t)(xo[p]+i)*DIM + lane*2);
    const float2 vp = *(const float2*)(descs + (size_t)(yo[p]+i)*DIM + lane*2);
    const float2 vn = *(const float2*)(descs + (size_t)orow*DIM + lane*2);
    float sap = va.x*vp.x + va.y*vp.y;
    float san = va.x*vn.x + va.y*vn.y;
    #pragma unroll
    for (int m=1;m<64;m<<=1){
      sap += __shfl_xor(sap, m, 64);
      san += __shfl_xor(san, m, 64);
    }
    if (lane == 0){
      const float rna = rnorm[xo[p]+i];
      const float dp = sap * rna * rnorm[yo[p]+i];
      const float dn = san * rna * rnorm[orow];
      pos[p*CNT + i] = dp; neg[p*CNT + i] = dn;
      const float omp_ = 1.f - dp, sqp = sqrtf(2.f*omp_ + 1e-12f), up = omp_ - sqp;
      const float omn_ = 1.f - dn, sqn = sqrtf(2.f*omn_ + 1e-12f), un = omn_ - sqn;
      u[p*CNT + i] = up;           v[p*CNT + i] = sqp;
      u[3*CNT + p*CNT + i] = un;   v[3*CNT + p*CNT + i] = sqn;
      const float cup = up + 0.35f, cvp = sqp - 0.80f;
      const float cun = un + 0.35f, cvn = sqn - 0.80f;
      s0 += up + un;
      s1 += sqp + sqn;
      s2 += cup*cup + cun*cun;
      s3 += cup*cvp + cun*cvn;
      s4 += cvp*cvp + cvn*cvn;
    }
  }
  if (lane == 0){ sred[w][0]=s0; sred[w][1]=s1; sred[w][2]=s2; sred[w][3]=s3; sred[w][4]=s4; }
  __syncthreads();
  if (tid < 5)
    mpart[b*5 + tid] = sred[0][tid] + sred[1][tid] + sred[2][tid] + sred[3][tid];
}

// kbce (moments folded): each block reduces the 192x5 mpart (L2-resident) then its 256-elem chunk
__global__ __launch_bounds__(256) void kbce(const float* __restrict__ u, const float* __restrict__ v,
    const float* __restrict__ mpart, float* __restrict__ psum){
  __shared__ float red[4];
  __shared__ float lu[256], lv[256];
  const int tid = threadIdx.x, b = blockIdx.x;
  lu[tid] = u[b*256 + tid];
  lv[tid] = v[b*256 + tid];
  float a0=0.f,a1=0.f,a2=0.f,a3=0.f,a4=0.f;
  if (tid < 192){
    const float* mp = mpart + (size_t)tid*5;
    a0=mp[0]; a1=mp[1]; a2=mp[2]; a3=mp[3]; a4=mp[4];
  }
  a0 = block_sum(a0, red, tid);
  a1 = block_sum(a1, red, tid);
  a2 = block_sum(a2, red, tid);
  a3 = block_sum(a3, red, tid);
  a4 = block_sum(a4, red, tid);      // barriers also publish lu/lv
  if (tid < 200){
    const float N = 49152.0f;
    const float mu_u = a0/N, mu_v = a1/N;
    const float du = mu_u + 0.35f, dv = mu_v - 0.80f;
    const float Suu = a2 - N*du*du;
    const float Suv = a3 - N*du*dv;
    const float Svv = a4 - N*dv*dv;
    const float a = -1.0f + 0.01f*(float)tid;
    const float mean = a*mu_u + mu_v;
    const float istd = 1.0f / sqrtf((a*a*Suu + 2.0f*a*Suv + Svv) / 49151.0f);
    const float sgn = (b < 96) ? 1.0f : -1.0f;     // first 3*CNT are label=1
    const float zi = istd*sgn;
    const float zm = mean*zi;
    float s = 0.0f;
    #pragma unroll 8
    for (int j=0;j<256;j++){
      const float z = fmaf(fmaf(a, lu[j], lv[j]), zi, -zm);
      s += fmaxf(z, 0.0f) + __logf(1.0f + __expf(-fabsf(z)));
    }
    psum[b*200 + tid] = s;
  }
}

// argmin(bce) -> alpha; losses, mask ratio, l_mean; 8 outputs
__global__ __launch_bounds__(256) void kfinal(const float* __restrict__ pos, const float* __restrict__ neg,
    const float* __restrict__ psum, const float* __restrict__ l_a_adv, const float* __restrict__ l_p_adv,
    float* __restrict__ out){
  __shared__ float sbce[200];
  __shared__ float sal[2];
  __shared__ float red[4];
  const int tid = threadIdx.x;
  if (tid < 200){
    float s = 0.f;
    for (int b=0;b<192;b++) s += psum[b*200 + tid];
    sbce[tid] = s;
  }
  __syncthreads();
  if (tid == 0){
    float best = sbce[0]; int bk = 0;
    for (int k=1;k<200;k++){
      const float vv = sbce[k];
      if (vv < best){ best = vv; bk = k; }
    }
    const float aopt = -1.0f + 0.01f*(float)bk;
    sal[0] = aopt;
    sal[1] = aopt * 0.005f;
  }
  __syncthreads();
  const float alpha = sal[1];

  float sc=0.f, sar=0.f, saa=0.f, sm=0.f, sla=0.f, slp=0.f;
  for (int i = tid; i < CNT; i += 256){
    const float pap = pos[i],        nap = neg[i];
    const float par = pos[CNT+i],    nar = neg[CNT+i];
    const float paa = pos[2*CNT+i],  naa = neg[2*CNT+i];
    const float cp = fminf(fmaxf(pap, -1.0f), 1.0f);
    const float cn = fminf(fmaxf(nap, -1.0f), 1.0f);
    const float m = (0.36f + acosf(cp) - acosf(cn) > 0.0f) ? 1.0f : 0.0f;
    #define DDIST(d) (alpha*(1.0f-(d)) + (1.0f-alpha)*sqrtf(2.0f*(1.0f-(d)) + 1e-12f))
    sc  += (DDIST(pap) - DDIST(nap)) * m;
    sar += (l_p_adv[i]*DDIST(par) - DDIST(nar)) * m;
    saa += (l_a_adv[i]*DDIST(paa) - DDIST(naa)) * m;
    sm  += m;
    sla += l_a_adv[i];
    slp += l_p_adv[i];
  }
  float vals[6] = {sc, sar, saa, sm, sla, slp};
  float tot[6];
  for (int vv=0; vv<6; vv++){
    tot[vv] = block_sum(vals[vv], red, tid);
  }
  if (tid == 0){
    const float lc  = tot[0] / (float)CNT;
    const float lar = tot[1] / (float)CNT;
    const float laa = tot[2] / (float)CNT;
    out[0] = (lc + lar + laa) / 3.0f;
    out[1] = lc;
    out[2] = lar;
    out[3] = laa;
    out[4] = (tot[4]/(float)CNT + tot[5]/(float)CNT) * 0.5f;
    out[5] = sal[1];
    out[6] = sal[0];
    out[7] = tot[3] / (float)CNT;
  }
}

extern "C" void kernel_launch(void* const* d_in, const int* in_sizes, int n_in,
                              void* d_out, int out_size, void* d_ws, size_t ws_size,
                              hipStream_t stream) {
  const float* descs = (const float*)d_in[0];
  const float* l_a   = (const float*)d_in[1];
  const float* l_p   = (const float*)d_in[2];
  float* out = (float*)d_out;
  char* ws = (char*)d_ws;

  float* pos = (float*)(ws + OFF_POS);
  float* neg = (float*)(ws + OFF_NEG);
  u32* rowpart = (u32*)(ws + OFF_ROWPART);
  u32* colpart = (u32*)(ws + OFF_COLPART);
  float* rnorm = (float*)(ws + OFF_RNORM);
  float* u     = (float*)(ws + OFF_U);
  float* v     = (float*)(ws + OFF_V);
  float* mpart = (float*)(ws + OFF_MPART);
  float* psum  = (float*)(ws + OFF_PSUM);
  unsigned int* xnb32 = (unsigned int*)(ws + OFF_XNB);
  const unsigned short* xnb = (const unsigned short*)(ws + OFF_XNB);

  knorm    <<<(6*CNT)/4, 256, 0, stream>>>(descs, xnb32, rnorm);
  kgemm    <<<dim3(64,64,3), 256, 0, stream>>>(xnb, rowpart, colpart);
  kpickred <<<192, 256, 0, stream>>>(descs, rnorm, rowpart, colpart, pos, neg, u, v, mpart);
  kbce     <<<192, 256, 0, stream>>>(u, v, mpart, psum);
  kfinal   <<<1, 256, 0, stream>>>(pos, neg, psum, l_a, l_p, out);
}

// Round 14
// 159.417 us; speedup vs baseline: 1.2990x; 1.0830x over previous
//
#include <hip/hip_runtime.h>
#include <stdint.h>

#define CNT 8192
#define DIM 128

typedef unsigned int u32;

// ---- workspace layout (bytes) ----
#define OFF_POS     ((size_t)0)                            // 3*CNT f32
#define OFF_NEG     (OFF_POS + (size_t)3*CNT*4)            // 3*CNT f32
#define OFF_FINROW  (OFF_NEG + (size_t)3*CNT*4)            // 3*CNT u32 (atomicMin targets)
#define OFF_FINCOL  (OFF_FINROW + (size_t)3*CNT*4)         // 3*CNT u32
#define OFF_RNORM   (OFF_FINCOL + (size_t)3*CNT*4)         // 6*CNT f32
#define OFF_U       (OFF_RNORM + (size_t)6*CNT*4)          // 6*CNT f32
#define OFF_V       (OFF_U + (size_t)6*CNT*4)              // 6*CNT f32
#define OFF_MPART   (OFF_V + (size_t)6*CNT*4)              // 6144*5 f32
#define OFF_PSUM    (OFF_MPART + (size_t)6144*5*4)         // 192*200 f32
#define OFF_XNB     (OFF_PSUM + (size_t)192*200*4)         // 6*CNT*DIM bf16
// total ~15 MiB

typedef __attribute__((ext_vector_type(8))) short short8;
typedef __attribute__((ext_vector_type(4))) float f32x4;

__device__ __forceinline__ float fract1(float x){
#if __has_builtin(__builtin_amdgcn_fractf)
  return __builtin_amdgcn_fractf(x);
#else
  return x - floorf(x);
#endif
}
__device__ __forceinline__ u32 umax2(u32 a, u32 b){ return a > b ? a : b; }
__device__ __forceinline__ u32 umax3(u32 a, u32 b, u32 c){ u32 t = a > b ? a : b; return t > c ? t : c; }

__device__ __forceinline__ float block_sum(float x, float* red, int tid){
  #pragma unroll
  for (int m=1;m<64;m<<=1) x += __shfl_xor(x, m, 64);
  if ((tid & 63) == 0) red[tid>>6] = x;
  __syncthreads();
  const float r = red[0]+red[1]+red[2]+red[3];
  __syncthreads();
  return r;
}

// row-normalize -> bf16 (A-side segments 0,2,4 pre-scaled by 0.25) + reciprocal norms
__global__ __launch_bounds__(256) void knorm(const float* __restrict__ in,
                                             unsigned int* __restrict__ xnb32,
                                             float* __restrict__ rnorm){
  const int row  = blockIdx.x*4 + (threadIdx.x>>6);
  const int lane = threadIdx.x & 63;
  const float2 v = *(const float2*)(in + (size_t)row*DIM + lane*2);
  float ss = v.x*v.x + v.y*v.y;
  #pragma unroll
  for (int m=1;m<64;m<<=1) ss += __shfl_xor(ss, m, 64);
  const float rn = 1.0f / sqrtf(ss);
  const float sc = ((row & CNT) ? 1.0f : 0.25f) * rn;
  unsigned int ux = __float_as_uint(v.x*sc), uy = __float_as_uint(v.y*sc);
  ux = (ux + 0x7FFFu + ((ux>>16)&1u)) >> 16;
  uy = (uy + 0x7FFFu + ((uy>>16)&1u)) >> 16;
  xnb32[(size_t)row*64 + lane] = ux | (uy<<16);
  if (lane == 0) rnorm[row] = rn;
}

// ---------------- MFMA bf16 GEMM, BK=32 dbuf (round-7 structure, proven ~84 us) ----------------
// acc = dot/4 (A pre-scaled). key = fract(acc): larger key == smaller dm (dm = 1/dot + eps).
// In-block packs: row [key25 | ~col7], col [key26 | ~row6] -> u32 max = argmax + lowest-idx ties.
// Global result: u32 [inv_key19 | index13] folded straight into finrow/fincol via atomicMin
// (commutative, exact on u32 -> deterministic and bit-identical to the old 2-stage reduce).
__global__ __launch_bounds__(256) void kgemm(const unsigned short* __restrict__ xnb,
    u32* __restrict__ finrow, u32* __restrict__ fincol){
  __shared__ __align__(16) unsigned short S[4][128*32];   // 32 KB: buf0{X,Y}, buf1{X,Y}
  const int pair = blockIdx.z;
  const int xo3[3] = {0, 2*CNT, 4*CNT};
  const int yo3[3] = {CNT, 5*CNT, 3*CNT};
  const unsigned short* __restrict__ X = xnb + (size_t)xo3[pair]*DIM;
  const unsigned short* __restrict__ Y = xnb + (size_t)yo3[pair]*DIM;
  const int brow = blockIdx.y*128, bcol = blockIdx.x*128;
  const int tid = threadIdx.x, lane = tid & 63, wid = tid >> 6;
  const int wr = wid >> 1, wc = wid & 1;           // 2x2 waves, 64x64 tiles
  const int lrow = lane & 15, kgrp = lane >> 4;

  // per-lane staging sources (16B/lane/inst), hoisted once; chunk advance folded into pointer
  const int j0 = wid*2, j1 = wid*2 + 1;
  const int r0 = j0*16 + (lane>>2), r1 = j1*16 + (lane>>2);
  const int slog = (lane&3) ^ ((lane>>3)&3);       // logical k-slot this phys slot holds
  const unsigned short* gx0 = X + (size_t)(brow + r0)*DIM + slog*8;
  const unsigned short* gx1 = X + (size_t)(brow + r1)*DIM + slog*8;
  const unsigned short* gy0 = Y + (size_t)(bcol + r0)*DIM + slog*8;
  const unsigned short* gy1 = Y + (size_t)(bcol + r1)*DIM + slog*8;

#define STAGEC(c) do{ \
    unsigned short* LX = S[((c)&1)*2]; \
    unsigned short* LY = S[((c)&1)*2 + 1]; \
    __builtin_amdgcn_global_load_lds((const __attribute__((address_space(1))) void*)(gx0 + (c)*32), \
        (__attribute__((address_space(3))) void*)(LX + j0*512), 16, 0, 0); \
    __builtin_amdgcn_global_load_lds((const __attribute__((address_space(1))) void*)(gx1 + (c)*32), \
        (__attribute__((address_space(3))) void*)(LX + j1*512), 16, 0, 0); \
    __builtin_amdgcn_global_load_lds((const __attribute__((address_space(1))) void*)(gy0 + (c)*32), \
        (__attribute__((address_space(3))) void*)(LY + j0*512), 16, 0, 0); \
    __builtin_amdgcn_global_load_lds((const __attribute__((address_space(1))) void*)(gy1 + (c)*32), \
        (__attribute__((address_space(3))) void*)(LY + j1*512), 16, 0, 0); \
  }while(0)

  f32x4 acc[4][4];
  #pragma unroll
  for (int m=0;m<4;m++)
    #pragma unroll
    for (int n=0;n<4;n++)
      acc[m][n] = (f32x4){0.f,0.f,0.f,0.f};

  STAGEC(0);
  __syncthreads();

  const int swzb = ((lrow>>1)&3) << 4;
  #pragma unroll
  for (int c=0;c<4;c++){
    if (c<3) STAGEC(c+1);
    const char* LX = (const char*)S[(c&1)*2];
    const char* LY = (const char*)S[(c&1)*2 + 1];
    const int kb = (kgrp*16) ^ swzb;
    short8 av[4], bv[4];
    #pragma unroll
    for (int m=0;m<4;m++){
      av[m] = *(const short8*)(LX + (wr*64 + m*16 + lrow)*64 + kb);
      bv[m] = *(const short8*)(LY + (wc*64 + m*16 + lrow)*64 + kb);
    }
    #pragma unroll
    for (int m=0;m<4;m++)
      #pragma unroll
      for (int n=0;n<4;n++)
        acc[m][n] = __builtin_amdgcn_mfma_f32_16x16x32_bf16(av[m], bv[n], acc[m][n], 0, 0, 0);
    if (c<3) __syncthreads();
  }

  // diagonal: acc=0 -> key 0 = minimal (reference adds BIG)
  if (blockIdx.x == blockIdx.y && wr == wc && kgrp == (lrow >> 2)){
    #pragma unroll
    for (int r=0;r<4;r++)
      if ((lrow & 3) == r){
        #pragma unroll
        for (int m=0;m<4;m++) acc[m][m][r] = 0.0f;
      }
  }

  // packing + max-trees (v_fract / v_and_or / v_max3 shaped)
  const int colb_loc = wc*64 + lrow;
  u32 orvr[4];
  #pragma unroll
  for (int n=0;n<4;n++) orvr[n] = (u32)(127 - colb_loc - n*16);

  u32 pkc[4] = {0u,0u,0u,0u};
  u32 rpk[16];
  #pragma unroll
  for (int m=0;m<4;m++){
    #pragma unroll
    for (int r=0;r<4;r++){
      const u32 orvc = (u32)(63 - (m*16 + kgrp*4 + r));
      u32 kb2[4];
      #pragma unroll
      for (int n=0;n<4;n++)
        kb2[n] = __float_as_uint(fract1(acc[m][n][r]));
      const u32 b0 = (kb2[0] & 0xFFFFFF80u) | orvr[0];
      const u32 b1 = (kb2[1] & 0xFFFFFF80u) | orvr[1];
      const u32 b2 = (kb2[2] & 0xFFFFFF80u) | orvr[2];
      const u32 b3 = (kb2[3] & 0xFFFFFF80u) | orvr[3];
      rpk[m*4+r] = umax2(umax3(b0, b1, b2), b3);
      pkc[0] = umax2(pkc[0], (kb2[0] & 0xFFFFFFC0u) | orvc);
      pkc[1] = umax2(pkc[1], (kb2[1] & 0xFFFFFFC0u) | orvc);
      pkc[2] = umax2(pkc[2], (kb2[2] & 0xFFFFFFC0u) | orvc);
      pkc[3] = umax2(pkc[3], (kb2[3] & 0xFFFFFFC0u) | orvc);
    }
  }

  // col: combine across kgrp lanes (row id embedded -> shuffle-max keeps winner)
  #pragma unroll
  for (int n=0;n<4;n++){
    u32 o = (u32)__shfl_xor((int)pkc[n], 16, 64); pkc[n] = umax2(pkc[n], o);
    o = (u32)__shfl_xor((int)pkc[n], 32, 64);     pkc[n] = umax2(pkc[n], o);
  }

  __syncthreads();                                  // tiles consumed; reuse LDS
  u32* rowbuf = (u32*)S;                            // [128][36] u32 = 18KB
  u32* colred = (u32*)((char*)S + 20480);           // [2][128] u32 = 1KB
  {
    const int slot = wc*16 + lrow;
    #pragma unroll
    for (int m=0;m<4;m++)
      #pragma unroll
      for (int r=0;r<4;r++){
        const int row = wr*64 + m*16 + kgrp*4 + r;
        rowbuf[row*36 + slot] = rpk[m*4+r];
      }
    if (kgrp == 0){
      #pragma unroll
      for (int n=0;n<4;n++)
        colred[wr*128 + wc*64 + n*16 + lrow] = pkc[n];
    }
  }
  __syncthreads();

  if (tid < 128){
    const u32* base = rowbuf + tid*36;
    u32 best = 0u;
    #pragma unroll
    for (int q=0;q<8;q++){
      const uint4 t = *(const uint4*)(base + q*4);
      best = umax2(best, umax2(umax3(t.x, t.y, t.z), t.w));
    }
    const int colg = 127 - (int)(best & 127u);
    atomicMin(&finrow[(size_t)pair*CNT + (brow + tid)],
              ((~best) & 0xFFFFE000u) | (u32)(bcol + colg));
  } else {
    const int c = tid - 128;
    const u32 a0 = colred[c], a1 = colred[128 + c];
    const u32 w = umax2(a0, a1);
    const int rloc = (a1 > a0 ? 64 : 0) + (63 - (int)(w & 63u));
    atomicMin(&fincol[(size_t)pair*CNT + (bcol + c)],
              ((~w) & 0xFFFFE000u) | (u32)(brow + rloc));
  }
#undef STAGEC
}

// pick hard negative + dots via rnorm + u,v + per-block moment partials (6144 blocks, 1 wave/entity)
__global__ __launch_bounds__(256) void kpick(const float* __restrict__ descs,
    const float* __restrict__ rnorm,
    const u32* __restrict__ finrow, const u32* __restrict__ fincol,
    float* __restrict__ pos, float* __restrict__ neg,
    float* __restrict__ u, float* __restrict__ v, float* __restrict__ mpart){
  __shared__ float sred[4][5];
  const int tid = threadIdx.x;
  const int w4 = tid >> 6, lane = tid & 63;
  const int e = blockIdx.x*4 + w4;                 // 0..24575
  const int p = e >> 13, i = e & (CNT-1);
  const int xo[3] = {0, 2*CNT, 4*CNT};
  const int yo[3] = {CNT, 5*CNT, 3*CNT};
  const u32 rv = finrow[(size_t)p*CNT + i];
  const u32 cv = fincol[(size_t)p*CNT + i];
  int orow;
  if ((rv & 0xFFFFE000u) < (cv & 0xFFFFE000u)) orow = yo[p] + (int)(rv & 0x1FFFu);
  else                                          orow = xo[p] + (int)(cv & 0x1FFFu);
  const float2 va = *(const float2*)(descs + (size_t)(xo[p]+i)*DIM + lane*2);
  const float2 vp = *(const float2*)(descs + (size_t)(yo[p]+i)*DIM + lane*2);
  const float2 vn = *(const float2*)(descs + (size_t)orow*DIM + lane*2);
  float sap = va.x*vp.x + va.y*vp.y;
  float san = va.x*vn.x + va.y*vn.y;
  #pragma unroll
  for (int m=1;m<64;m<<=1){
    sap += __shfl_xor(sap, m, 64);
    san += __shfl_xor(san, m, 64);
  }
  if (lane == 0){
    const float rna = rnorm[xo[p]+i];
    const float dp = sap * rna * rnorm[yo[p]+i];
    const float dn = san * rna * rnorm[orow];
    pos[p*CNT + i] = dp; neg[p*CNT + i] = dn;
    const float omp_ = 1.f - dp, sqp = sqrtf(2.f*omp_ + 1e-12f), up = omp_ - sqp;
    const float omn_ = 1.f - dn, sqn = sqrtf(2.f*omn_ + 1e-12f), un = omn_ - sqn;
    u[p*CNT + i] = up;           v[p*CNT + i] = sqp;
    u[3*CNT + p*CNT + i] = un;   v[3*CNT + p*CNT + i] = sqn;
    const float cup = up + 0.35f, cvp = sqp - 0.80f;
    const float cun = un + 0.35f, cvn = sqn - 0.80f;
    sred[w4][0] = up + un;
    sred[w4][1] = sqp + sqn;
    sred[w4][2] = cup*cup + cun*cun;
    sred[w4][3] = cup*cvp + cun*cvn;
    sred[w4][4] = cvp*cvp + cvn*cvn;
  }
  __syncthreads();
  if (tid < 5)
    mpart[blockIdx.x*5 + tid] = sred[0][tid] + sred[1][tid] + sred[2][tid] + sred[3][tid];
}

// kbce (moments folded): each block reduces the 6144x5 mpart (L2-resident) then its 256-elem chunk
__global__ __launch_bounds__(256) void kbce(const float* __restrict__ u, const float* __restrict__ v,
    const float* __restrict__ mpart, float* __restrict__ psum){
  __shared__ float red[4];
  __shared__ float lu[256], lv[256];
  const int tid = threadIdx.x, b = blockIdx.x;
  lu[tid] = u[b*256 + tid];
  lv[tid] = v[b*256 + tid];
  float a0=0.f,a1=0.f,a2=0.f,a3=0.f,a4=0.f;
  for (int i = tid; i < 6144; i += 256){
    const float* mp = mpart + (size_t)i*5;
    a0+=mp[0]; a1+=mp[1]; a2+=mp[2]; a3+=mp[3]; a4+=mp[4];
  }
  a0 = block_sum(a0, red, tid);
  a1 = block_sum(a1, red, tid);
  a2 = block_sum(a2, red, tid);
  a3 = block_sum(a3, red, tid);
  a4 = block_sum(a4, red, tid);      // barriers also publish lu/lv
  if (tid < 200){
    const float N = 49152.0f;
    const float mu_u = a0/N, mu_v = a1/N;
    const float du = mu_u + 0.35f, dv = mu_v - 0.80f;
    const float Suu = a2 - N*du*du;
    const float Suv = a3 - N*du*dv;
    const float Svv = a4 - N*dv*dv;
    const float a = -1.0f + 0.01f*(float)tid;
    const float mean = a*mu_u + mu_v;
    const float istd = 1.0f / sqrtf((a*a*Suu + 2.0f*a*Suv + Svv) / 49151.0f);
    const float sgn = (b < 96) ? 1.0f : -1.0f;     // first 3*CNT are label=1
    const float zi = istd*sgn;
    const float zm = mean*zi;
    float s = 0.0f;
    #pragma unroll 8
    for (int j=0;j<256;j++){
      const float z = fmaf(fmaf(a, lu[j], lv[j]), zi, -zm);
      s += fmaxf(z, 0.0f) + __logf(1.0f + __expf(-fabsf(z)));
    }
    psum[b*200 + tid] = s;
  }
}

// argmin(bce) -> alpha; losses, mask ratio, l_mean; 8 outputs
__global__ __launch_bounds__(256) void kfinal(const float* __restrict__ pos, const float* __restrict__ neg,
    const float* __restrict__ psum, const float* __restrict__ l_a_adv, const float* __restrict__ l_p_adv,
    float* __restrict__ out){
  __shared__ float sbce[200];
  __shared__ float sal[2];
  __shared__ float red[4];
  const int tid = threadIdx.x;
  if (tid < 200){
    float s = 0.f;
    for (int b=0;b<192;b++) s += psum[b*200 + tid];
    sbce[tid] = s;
  }
  __syncthreads();
  if (tid == 0){
    float best = sbce[0]; int bk = 0;
    for (int k=1;k<200;k++){
      const float vv = sbce[k];
      if (vv < best){ best = vv; bk = k; }
    }
    const float aopt = -1.0f + 0.01f*(float)bk;
    sal[0] = aopt;
    sal[1] = aopt * 0.005f;
  }
  __syncthreads();
  const float alpha = sal[1];

  float sc=0.f, sar=0.f, saa=0.f, sm=0.f, sla=0.f, slp=0.f;
  for (int i = tid; i < CNT; i += 256){
    const float pap = pos[i],        nap = neg[i];
    const float par = pos[CNT+i],    nar = neg[CNT+i];
    const float paa = pos[2*CNT+i],  naa = neg[2*CNT+i];
    const float cp = fminf(fmaxf(pap, -1.0f), 1.0f);
    const float cn = fminf(fmaxf(nap, -1.0f), 1.0f);
    const float m = (0.36f + acosf(cp) - acosf(cn) > 0.0f) ? 1.0f : 0.0f;
    #define DDIST(d) (alpha*(1.0f-(d)) + (1.0f-alpha)*sqrtf(2.0f*(1.0f-(d)) + 1e-12f))
    sc  += (DDIST(pap) - DDIST(nap)) * m;
    sar += (l_p_adv[i]*DDIST(par) - DDIST(nar)) * m;
    saa += (l_a_adv[i]*DDIST(paa) - DDIST(naa)) * m;
    sm  += m;
    sla += l_a_adv[i];
    slp += l_p_adv[i];
  }
  float vals[6] = {sc, sar, saa, sm, sla, slp};
  float tot[6];
  for (int vv=0; vv<6; vv++){
    tot[vv] = block_sum(vals[vv], red, tid);
  }
  if (tid == 0){
    const float lc  = tot[0] / (float)CNT;
    const float lar = tot[1] / (float)CNT;
    const float laa = tot[2] / (float)CNT;
    out[0] = (lc + lar + laa) / 3.0f;
    out[1] = lc;
    out[2] = lar;
    out[3] = laa;
    out[4] = (tot[4]/(float)CNT + tot[5]/(float)CNT) * 0.5f;
    out[5] = sal[1];
    out[6] = sal[0];
    out[7] = tot[3] / (float)CNT;
  }
}

extern "C" void kernel_launch(void* const* d_in, const int* in_sizes, int n_in,
                              void* d_out, int out_size, void* d_ws, size_t ws_size,
                              hipStream_t stream) {
  const float* descs = (const float*)d_in[0];
  const float* l_a   = (const float*)d_in[1];
  const float* l_p   = (const float*)d_in[2];
  float* out = (float*)d_out;
  char* ws = (char*)d_ws;

  float* pos = (float*)(ws + OFF_POS);
  float* neg = (float*)(ws + OFF_NEG);
  u32* finrow  = (u32*)(ws + OFF_FINROW);
  u32* fincol  = (u32*)(ws + OFF_FINCOL);
  float* rnorm = (float*)(ws + OFF_RNORM);
  float* u     = (float*)(ws + OFF_U);
  float* v     = (float*)(ws + OFF_V);
  float* mpart = (float*)(ws + OFF_MPART);
  float* psum  = (float*)(ws + OFF_PSUM);
  unsigned int* xnb32 = (unsigned int*)(ws + OFF_XNB);
  const unsigned short* xnb = (const unsigned short*)(ws + OFF_XNB);

  // init atomicMin targets to 0xFFFFFFFF (graph-capturable async memset)
  hipMemsetAsync(finrow, 0xFF, (size_t)2*3*CNT*4, stream);   // finrow+fincol contiguous

  knorm  <<<(6*CNT)/4, 256, 0, stream>>>(descs, xnb32, rnorm);
  kgemm  <<<dim3(64,64,3), 256, 0, stream>>>(xnb, finrow, fincol);
  kpick  <<<(3*CNT)/4, 256, 0, stream>>>(descs, rnorm, finrow, fincol, pos, neg, u, v, mpart);
  kbce   <<<192, 256, 0, stream>>>(u, v, mpart, psum);
  kfinal <<<1, 256, 0, stream>>>(pos, neg, psum, l_a, l_p, out);
}